// Round 1
// baseline (1498.587 us; speedup 1.0000x reference)
//
#include <hip/hip_runtime.h>
#include <cstdint>

typedef unsigned short u16;
typedef __attribute__((ext_vector_type(8))) short short8;  // 8 bf16 (4 VGPRs)
typedef __attribute__((ext_vector_type(4))) float f32x4;

__device__ __forceinline__ u16 f32_to_bf16(float f) {
    unsigned u = __builtin_bit_cast(unsigned, f);
    u += 0x7FFFu + ((u >> 16) & 1u);   // RNE
    return (u16)(u >> 16);
}

// ---------------- embed lookup + bf16 cast: xb[b*512+s][e] ----------------
__global__ __launch_bounds__(256) void embed_cast(const int* __restrict__ tok,
                                                  const float* __restrict__ emb,
                                                  u16* __restrict__ xb) {
    const int i = blockIdx.x;                 // 0..16383 token index
    const long t = tok[i];
    const float4 f = ((const float4*)(emb + t * 1024))[threadIdx.x];
    unsigned lo = (unsigned)f32_to_bf16(f.x) | ((unsigned)f32_to_bf16(f.y) << 16);
    unsigned hi = (unsigned)f32_to_bf16(f.z) | ((unsigned)f32_to_bf16(f.w) << 16);
    ((uint2*)(xb + (long)i * 1024))[threadIdx.x] = make_uint2(lo, hi);
}

// ------------- W [K][N] f32  ->  Wt [Npad][K] bf16 (zero-pad n>=N) -------------
__global__ __launch_bounds__(256) void transpose_conv(const float* __restrict__ W,
                                                      u16* __restrict__ Wt,
                                                      int K, int N) {
    __shared__ float t[32][33];
    const int kb = blockIdx.x * 32, nb = blockIdx.y * 32;
    const int tx = threadIdx.x, ty = threadIdx.y;   // 32 x 8
    #pragma unroll
    for (int j = 0; j < 32; j += 8) {
        const int n = nb + tx;
        t[ty + j][tx] = (n < N) ? W[(long)(kb + ty + j) * N + n] : 0.f;
    }
    __syncthreads();
    #pragma unroll
    for (int j = 0; j < 32; j += 8)
        Wt[(long)(nb + ty + j) * K + kb + tx] = f32_to_bf16(t[tx][ty + j]);
}

// ---------------- pad bv [8][36] -> bvp [8][128] ----------------
__global__ void pad_bv(const float* __restrict__ bv, float* __restrict__ bvp) {
    int i = blockIdx.x * 256 + threadIdx.x;   // 0..1023
    int h = i >> 7, n = i & 127;
    bvp[i] = (n < 36) ? bv[h * 36 + n] : 0.f;
}

// ------------------------------------------------------------------
// GEMM: C[m][n] = act(scale * sum_k A[m][k]*Bt[n][k] + bias[n])
// A,Bt bf16; 128x128 tile, BK=64, 4 waves (2x2, each 64x64 = 4x4 MFMA frags).
// global_load_lds w16 -> linear LDS; XOR swizzle (col8 ^= row&7) applied on
// the GLOBAL source and the ds_read address (rule 21 both-sides).
// ------------------------------------------------------------------
template<bool RELU, bool CBF16, bool TRANSC, bool HASBIAS>
__global__ __launch_bounds__(256, 2)
void gemm_bt(const u16* __restrict__ A, const u16* __restrict__ Bt,
             void* __restrict__ Cv, const float* __restrict__ bias,
             int K, int lda, int ldb, int ldc, float scale,
             long sA, long sB, long sC)
{
    __shared__ __attribute__((aligned(16))) u16 As[128 * 64];
    __shared__ __attribute__((aligned(16))) u16 Bs[128 * 64];
    const int z = blockIdx.z;
    const u16* Ab = A + (long)z * sA;
    const u16* Bb = Bt + (long)z * sB;
    const long crow0 = (long)blockIdx.x * 128;
    const long ccol0 = (long)blockIdx.y * 128;
    const int tid = threadIdx.x;
    const int lane = tid & 63;
    const int wv = tid >> 6;
    const int wm = wv >> 1, wn = wv & 1;

    f32x4 acc[4][4] = {};

    const int srow = (wv << 3) + (lane >> 3);  // row within 32-row staging group
    const int sc8 = lane & 7;                  // 16B chunk within 128B row

    for (int k0 = 0; k0 < K; k0 += 64) {
        __syncthreads();   // previous tile fully consumed
        #pragma unroll
        for (int i = 0; i < 4; ++i) {
            const int r = i * 32 + srow;
            const int c8 = sc8 ^ (r & 7);      // pre-swizzled global source
            const u16* ga = Ab + (crow0 + r) * (long)lda + k0 + c8 * 8;
            const u16* gb = Bb + (ccol0 + r) * (long)ldb + k0 + c8 * 8;
            __builtin_amdgcn_global_load_lds(
                (__attribute__((address_space(1))) void*)ga,
                (__attribute__((address_space(3))) void*)(&As[(i * 32 + wv * 8) * 64]),
                16, 0, 0);
            __builtin_amdgcn_global_load_lds(
                (__attribute__((address_space(1))) void*)gb,
                (__attribute__((address_space(3))) void*)(&Bs[(i * 32 + wv * 8) * 64]),
                16, 0, 0);
        }
        __syncthreads();   // vmcnt drained by barrier semantics

        #pragma unroll
        for (int ks = 0; ks < 2; ++ks) {
            short8 af[4], bfr[4];
            const int kg = ks * 4 + (lane >> 4);
            #pragma unroll
            for (int mf = 0; mf < 4; ++mf) {
                const int r = wm * 64 + mf * 16 + (lane & 15);
                af[mf] = *(const short8*)&As[r * 64 + ((kg ^ (r & 7)) << 3)];
            }
            #pragma unroll
            for (int nf = 0; nf < 4; ++nf) {
                const int r = wn * 64 + nf * 16 + (lane & 15);
                bfr[nf] = *(const short8*)&Bs[r * 64 + ((kg ^ (r & 7)) << 3)];
            }
            #pragma unroll
            for (int mf = 0; mf < 4; ++mf)
                #pragma unroll
                for (int nf = 0; nf < 4; ++nf)
                    acc[mf][nf] = __builtin_amdgcn_mfma_f32_16x16x32_bf16(
                        af[mf], bfr[nf], acc[mf][nf], 0, 0, 0);
        }
    }

    char* Cb = (char*)Cv + (long)z * sC * (CBF16 ? 2 : 4);
    #pragma unroll
    for (int mf = 0; mf < 4; ++mf) {
        #pragma unroll
        for (int nf = 0; nf < 4; ++nf) {
            const long col = ccol0 + wn * 64 + nf * 16 + (lane & 15);
            float bval = 0.f;
            if (HASBIAS) bval = bias[col];
            #pragma unroll
            for (int rr = 0; rr < 4; ++rr) {
                const long row = crow0 + wm * 64 + mf * 16 + ((lane >> 4) << 2) + rr;
                float v = acc[mf][nf][rr] * scale + bval;
                if (RELU) v = fmaxf(v, 0.f);
                const long idx = TRANSC ? (col * (long)ldc + row) : (row * (long)ldc + col);
                if (CBF16) ((u16*)Cb)[idx] = f32_to_bf16(v);
                else       ((float*)Cb)[idx] = v;
            }
        }
    }
}

// ----- softmax over rows of 512, in place: f32 row -> bf16 packed at row start -----
__global__ __launch_bounds__(256) void softmax_inplace(float* __restrict__ sc) {
    const int row = blockIdx.x * 4 + (threadIdx.x >> 6);
    const int lane = threadIdx.x & 63;
    float* r = sc + (long)row * 512;
    const float4 a = ((const float4*)r)[lane * 2];
    const float4 b = ((const float4*)r)[lane * 2 + 1];
    float e[8] = {a.x, a.y, a.z, a.w, b.x, b.y, b.z, b.w};
    float m = e[0];
    #pragma unroll
    for (int j = 1; j < 8; ++j) m = fmaxf(m, e[j]);
    #pragma unroll
    for (int o = 32; o; o >>= 1) m = fmaxf(m, __shfl_xor(m, o));
    float s = 0.f;
    #pragma unroll
    for (int j = 0; j < 8; ++j) { e[j] = __expf(e[j] - m); s += e[j]; }
    #pragma unroll
    for (int o = 32; o; o >>= 1) s += __shfl_xor(s, o);
    const float inv = 1.f / s;
    uint4 pk;
    pk.x = (unsigned)f32_to_bf16(e[0] * inv) | ((unsigned)f32_to_bf16(e[1] * inv) << 16);
    pk.y = (unsigned)f32_to_bf16(e[2] * inv) | ((unsigned)f32_to_bf16(e[3] * inv) << 16);
    pk.z = (unsigned)f32_to_bf16(e[4] * inv) | ((unsigned)f32_to_bf16(e[5] * inv) << 16);
    pk.w = (unsigned)f32_to_bf16(e[6] * inv) | ((unsigned)f32_to_bf16(e[7] * inv) << 16);
    ((uint4*)r)[lane] = pk;   // safe: all lanes' reads precede (shfl dependency)
}

// ----- per-head FC partial: part[h][b][c] = sum_{s,v} outh[b*512+s][v] * fcw[c][s*288+h*36+v] -----
__global__ __launch_bounds__(256) void reduce_head(const float* __restrict__ outh,
                                                   const float* __restrict__ fcw,
                                                   float* __restrict__ part, int h) {
    const int b = blockIdx.x, tid = threadIdx.x;
    const float* ob = outh + (long)b * 512 * 128;
    const float* w0 = fcw + (long)h * 36;
    const float* w1 = fcw + 147456 + (long)h * 36;
    float a0 = 0.f, a1 = 0.f;
    for (int i = tid; i < 512 * 36; i += 256) {
        const int s = i / 36, v = i - s * 36;
        const float f = ob[s * 128 + v];
        a0 += f * w0[(long)s * 288 + v];
        a1 += f * w1[(long)s * 288 + v];
    }
    __shared__ float r0[256], r1[256];
    r0[tid] = a0; r1[tid] = a1;
    __syncthreads();
    for (int o = 128; o; o >>= 1) {
        if (tid < o) { r0[tid] += r0[tid + o]; r1[tid] += r1[tid + o]; }
        __syncthreads();
    }
    if (tid == 0) { part[(h * 32 + b) * 2] = r0[0]; part[(h * 32 + b) * 2 + 1] = r1[0]; }
}

// ----- final: logits -> sigmoid -> log_softmax; out = [pred(64) | score(64)] -----
__global__ void final_k(const float* __restrict__ part, const float* __restrict__ fcb,
                        float* __restrict__ out) {
    const int b = threadIdx.x;
    if (b >= 32) return;
    float l0 = fcb[0], l1 = fcb[1];
    #pragma unroll
    for (int h = 0; h < 8; ++h) { l0 += part[(h * 32 + b) * 2]; l1 += part[(h * 32 + b) * 2 + 1]; }
    const float s0 = 1.f / (1.f + expf(-l0));
    const float s1 = 1.f / (1.f + expf(-l1));
    const float mm = fmaxf(s0, s1);
    const float lse = mm + logf(expf(s0 - mm) + expf(s1 - mm));
    out[b * 2] = s0 - lse; out[b * 2 + 1] = s1 - lse;
    out[64 + b * 2] = s0;  out[64 + b * 2 + 1] = s1;
}

extern "C" void kernel_launch(void* const* d_in, const int* in_sizes, int n_in,
                              void* d_out, int out_size, void* d_ws, size_t ws_size,
                              hipStream_t stream) {
    (void)in_sizes; (void)n_in;
    const int*   tokens = (const int*)  d_in[0];
    const float* emb    = (const float*)d_in[1];
    const float* Wq     = (const float*)d_in[2];
    const float* bq     = (const float*)d_in[3];
    const float* Wk     = (const float*)d_in[4];
    const float* bk     = (const float*)d_in[5];
    const float* Wv     = (const float*)d_in[6];
    const float* bv     = (const float*)d_in[7];
    const float* fcw    = (const float*)d_in[8];
    const float* fcb    = (const float*)d_in[9];
    float* out = (float*)d_out;

    char* wsp = (char*)d_ws;
    size_t need = 0;
    auto alloc = [&](size_t bytes) {
        char* p = wsp + need;
        need += (bytes + 255) & ~(size_t)255;
        return p;
    };
    u16*   xb     = (u16*)  alloc(16384L * 1024 * 2);  // embedded tokens bf16
    u16*   Qh     = (u16*)  alloc(16384L * 1024 * 2);  // per-head Q bf16
    u16*   Kh     = (u16*)  alloc(16384L * 1024 * 2);  // per-head K bf16
    float* scores = (float*)alloc(32L * 512 * 512 * 4); // scores f32 / attn bf16 in-place
    u16*   Vt     = (u16*)  alloc(128L * 16384 * 2);   // V transposed bf16 [128][16384]
    float* outh   = (float*)alloc(16384L * 128 * 4);   // attention output f32
    u16*   Wqt    = (u16*)  alloc(1024L * 1024 * 2);
    u16*   Wkt    = (u16*)  alloc(1024L * 1024 * 2);
    u16*   Wvt    = (u16*)  alloc(128L * 1024 * 2);
    float* bvp    = (float*)alloc(8L * 128 * 4);
    float* part   = (float*)alloc(8L * 32 * 2 * 4);
    if (ws_size < need) {   // recognizable failure mode: all-zero output
        hipMemsetAsync(d_out, 0, (size_t)out_size * 4, stream);
        return;
    }

    embed_cast<<<16384, 256, 0, stream>>>(tokens, emb, xb);
    pad_bv<<<4, 256, 0, stream>>>(bv, bvp);

    for (int h = 0; h < 8; ++h) {
        transpose_conv<<<dim3(32, 32), dim3(32, 8), 0, stream>>>(Wq + (long)h * 1024 * 1024, Wqt, 1024, 1024);
        transpose_conv<<<dim3(32, 32), dim3(32, 8), 0, stream>>>(Wk + (long)h * 1024 * 1024, Wkt, 1024, 1024);
        transpose_conv<<<dim3(32, 4),  dim3(32, 8), 0, stream>>>(Wv + (long)h * 1024 * 36,  Wvt, 1024, 36);

        // Q/K = relu(xb @ W^T + b) -> bf16 [16384][1024]
        gemm_bt<true, true, false, true><<<dim3(128, 8, 1), 256, 0, stream>>>(
            xb, Wqt, Qh, bq + h * 1024, 1024, 1024, 1024, 1024, 1.f, 0, 0, 0);
        gemm_bt<true, true, false, true><<<dim3(128, 8, 1), 256, 0, stream>>>(
            xb, Wkt, Kh, bk + h * 1024, 1024, 1024, 1024, 1024, 1.f, 0, 0, 0);
        // Vt[n][m] = relu(xb @ Wv^T + bv)  (transposed store) bf16 [128][16384]
        gemm_bt<true, true, true, true><<<dim3(128, 1, 1), 256, 0, stream>>>(
            xb, Wvt, Vt, bvp + h * 128, 1024, 1024, 1024, 16384, 1.f, 0, 0, 0);
        // scores[z] = (Q[z] @ K[z]^T) / 32   f32 [512][512], z = batch
        gemm_bt<false, false, false, false><<<dim3(4, 4, 32), 256, 0, stream>>>(
            Qh, Kh, scores, nullptr, 1024, 1024, 1024, 512, 0.03125f,
            512L * 1024, 512L * 1024, 512L * 512);
        softmax_inplace<<<4096, 256, 0, stream>>>(scores);
        // outh[z] = attn[z] @ Vt[:, z*512:z*512+512]^T   f32 [512][128]
        gemm_bt<false, false, false, false><<<dim3(4, 1, 32), 256, 0, stream>>>(
            (const u16*)scores, Vt, outh, nullptr, 512, 1024, 16384, 128, 1.f,
            512L * 1024, 512, 512L * 128);
        reduce_head<<<32, 256, 0, stream>>>(outh, fcw, part, h);
    }
    final_k<<<1, 64, 0, stream>>>(part, fcb, out);
}

// Round 2
// 1394.723 us; speedup vs baseline: 1.0745x; 1.0745x over previous
//
#include <hip/hip_runtime.h>
#include <cstdint>

typedef unsigned short u16;
typedef __attribute__((ext_vector_type(8))) short short8;  // 8 bf16 (4 VGPRs)
typedef __attribute__((ext_vector_type(4))) float f32x4;

__device__ __forceinline__ u16 f32_to_bf16(float f) {
    unsigned u = __builtin_bit_cast(unsigned, f);
    u += 0x7FFFu + ((u >> 16) & 1u);   // RNE
    return (u16)(u >> 16);
}

// ---------------- embed lookup + bf16 cast: xb[b*512+s][e] ----------------
__global__ __launch_bounds__(256) void embed_cast(const int* __restrict__ tok,
                                                  const float* __restrict__ emb,
                                                  u16* __restrict__ xb) {
    const int i = blockIdx.x;                 // 0..16383 token index
    const long t = tok[i];
    const float4 f = ((const float4*)(emb + t * 1024))[threadIdx.x];
    unsigned lo = (unsigned)f32_to_bf16(f.x) | ((unsigned)f32_to_bf16(f.y) << 16);
    unsigned hi = (unsigned)f32_to_bf16(f.z) | ((unsigned)f32_to_bf16(f.w) << 16);
    ((uint2*)(xb + (long)i * 1024))[threadIdx.x] = make_uint2(lo, hi);
}

// ------ Wq/Wk [h][1024][1024] f32 -> WqkT [h][2048][1024] bf16 (rows 0-1023=Wq^T, 1024-2047=Wk^T) ------
__global__ __launch_bounds__(256) void transpose_qk(const float* __restrict__ Wq,
                                                    const float* __restrict__ Wk,
                                                    u16* __restrict__ WqkT) {
    const int z = blockIdx.z;                 // h*2 + m
    const int h = z >> 1, m = z & 1;
    const float* W = (m ? Wk : Wq) + (long)h * 1048576;
    u16* out = WqkT + (long)z * 1048576;
    __shared__ float tt[32][33];
    const int kb = blockIdx.x * 32, nb = blockIdx.y * 32;
    const int tx = threadIdx.x, ty = threadIdx.y;   // 32 x 8
    #pragma unroll
    for (int j = 0; j < 32; j += 8)
        tt[ty + j][tx] = W[(long)(kb + ty + j) * 1024 + nb + tx];
    __syncthreads();
    #pragma unroll
    for (int j = 0; j < 32; j += 8)
        out[(long)(nb + ty + j) * 1024 + kb + tx] = f32_to_bf16(tt[tx][ty + j]);
}

// ------ Wv [h][1024][36] f32 -> WvT [h*128 + v][1024] bf16, zero-pad v>=36 ------
__global__ __launch_bounds__(256) void transpose_v(const float* __restrict__ Wv,
                                                   u16* __restrict__ WvT) {
    const int h = blockIdx.z;
    const float* W = Wv + (long)h * 1024 * 36;
    u16* out = WvT + (long)h * 128 * 1024;
    __shared__ float tt[32][33];
    const int kb = blockIdx.x * 32, nb = blockIdx.y * 32;   // nb in 0..96
    const int tx = threadIdx.x, ty = threadIdx.y;
    #pragma unroll
    for (int j = 0; j < 32; j += 8) {
        const int n = nb + tx;
        tt[ty + j][tx] = (n < 36) ? W[(long)(kb + ty + j) * 36 + n] : 0.f;
    }
    __syncthreads();
    #pragma unroll
    for (int j = 0; j < 32; j += 8)
        out[(long)(nb + ty + j) * 1024 + kb + tx] = f32_to_bf16(tt[tx][ty + j]);
}

// ---------------- bias stack: bqk[h][2048] = [bq[h] | bk[h]] ----------------
__global__ void stack_bias(const float* __restrict__ bq, const float* __restrict__ bk,
                           float* __restrict__ bqk) {
    const int i = blockIdx.x * 256 + threadIdx.x;   // < 16384
    const int h = i >> 11, c = i & 2047;
    bqk[i] = (c < 1024) ? bq[h * 1024 + c] : bk[h * 1024 + c - 1024];
}

// ---------------- pad bv [8][36] -> bvp [8][128] ----------------
__global__ void pad_bv(const float* __restrict__ bv, float* __restrict__ bvp) {
    int i = blockIdx.x * 256 + threadIdx.x;   // 0..1023
    int h = i >> 7, n = i & 127;
    bvp[i] = (n < 36) ? bv[h * 36 + n] : 0.f;
}

// ==================================================================
// 8-phase 256x256 GEMM (T2+T3+T4+T5), BK=64, 8 waves (2Mx4N), 512 thr.
// LDS regions: [buf][khalf][op][256 rows][32 cols] bf16 = 128 KiB.
// Refill schedule (tile t, buf c=t&1):
//   P1 issue (c^1).k1 <- tile t+1 ; P3 issue (c).k0 <- tile t+2
//   P4: s_waitcnt vmcnt(4) (steady) -> next tile fully landed at close barrier.
// Region-death proof: k0 of buf c last read P2 (refilled P3, after P2 close);
// k1 of buf c last read P4 (refilled next-iter P1, after P4 close+sched_barrier).
// Requires nt >= 2. Both-sides XOR swizzle chunk^=(row&3) on 16B chunks.
// ==================================================================
template<bool RELU, bool CBF16, bool TRANSC, bool HASBIAS>
__global__ __launch_bounds__(512, 2)
void gemm8(const u16* __restrict__ A, const u16* __restrict__ Bt,
           void* __restrict__ Cv, const float* __restrict__ bias,
           int K, int lda, int ldb, int ldc, float scale,
           long sA, long sB, long sC)
{
    __shared__ __attribute__((aligned(16))) u16 lds[2][2][2][256 * 32];
    const int z = blockIdx.z;
    const u16* Ab = A + (long)z * sA;
    const u16* Bb = Bt + (long)z * sB;
    const long crow0 = (long)blockIdx.x * 256;
    const long ccol0 = (long)blockIdx.y * 256;
    const int tid = threadIdx.x;
    const int lane = tid & 63;
    const int wv = tid >> 6;          // 0..7
    const int wm = wv >> 2;           // 0..1
    const int wn = wv & 3;            // 0..3
    const int nt = K >> 6;

    const int srow4 = lane >> 2;      // 0..15
    const int schunk = lane & 3;

    auto stagePair = [&](int buf, int kh, long t) {   // 4 loads/thread: A+B of one k-half
        const long kbase = t * 64 + kh * 32;
        #pragma unroll
        for (int j = 0; j < 2; ++j) {
            const int row = j * 128 + wv * 16 + srow4;
            const int c = schunk ^ (row & 3);         // pre-swizzled global source
            const u16* ga = Ab + (crow0 + row) * (long)lda + kbase + c * 8;
            const u16* gb = Bb + (ccol0 + row) * (long)ldb + kbase + c * 8;
            __builtin_amdgcn_global_load_lds(
                (__attribute__((address_space(1))) void*)ga,
                (__attribute__((address_space(3))) void*)(&lds[buf][kh][0][(j * 128 + wv * 16) * 32]),
                16, 0, 0);
            __builtin_amdgcn_global_load_lds(
                (__attribute__((address_space(1))) void*)gb,
                (__attribute__((address_space(3))) void*)(&lds[buf][kh][1][(j * 128 + wv * 16) * 32]),
                16, 0, 0);
        }
    };

    f32x4 acc[8][4] = {};
    short8 af[8], bf2[2];

    auto readA = [&](int buf, int ks) {
        #pragma unroll
        for (int mf = 0; mf < 8; ++mf) {
            const int row = wm * 128 + mf * 16 + (lane & 15);
            af[mf] = *(const short8*)&lds[buf][ks][0][row * 32 + (((lane >> 4) ^ (row & 3)) << 3)];
        }
    };
    auto readB = [&](int buf, int ks, int nh) {
        #pragma unroll
        for (int i = 0; i < 2; ++i) {
            const int row = wn * 64 + (nh * 2 + i) * 16 + (lane & 15);
            bf2[i] = *(const short8*)&lds[buf][ks][1][row * 32 + (((lane >> 4) ^ (row & 3)) << 3)];
        }
    };
    auto MMA = [&](int nh) {
        __builtin_amdgcn_s_setprio(1);
        #pragma unroll
        for (int mf = 0; mf < 8; ++mf) {
            acc[mf][nh * 2]     = __builtin_amdgcn_mfma_f32_16x16x32_bf16(af[mf], bf2[0], acc[mf][nh * 2], 0, 0, 0);
            acc[mf][nh * 2 + 1] = __builtin_amdgcn_mfma_f32_16x16x32_bf16(af[mf], bf2[1], acc[mf][nh * 2 + 1], 0, 0, 0);
        }
        __builtin_amdgcn_s_setprio(0);
    };

    // prologue: tile0 (both halves) + tile1.k0 = 12 loads; wait all but newest 4
    stagePair(0, 0, 0);
    stagePair(0, 1, 0);
    stagePair(1, 0, 1);
    asm volatile("s_waitcnt vmcnt(4)" ::: "memory");
    __builtin_amdgcn_s_barrier();
    __builtin_amdgcn_sched_barrier(0);

    for (long t = 0; t < nt; ++t) {
        const int c = (int)(t & 1);
        // ---- P1: ks0, nf{0,1} ----
        readA(c, 0);
        readB(c, 0, 0);
        if (t + 1 < nt) stagePair(c ^ 1, 1, t + 1);
        __builtin_amdgcn_s_barrier();
        MMA(0);
        __builtin_amdgcn_s_barrier();
        __builtin_amdgcn_sched_barrier(0);
        // ---- P2: ks0, nf{2,3} ----
        readB(c, 0, 1);
        __builtin_amdgcn_s_barrier();
        MMA(1);
        __builtin_amdgcn_s_barrier();
        __builtin_amdgcn_sched_barrier(0);
        // ---- P3: ks1, nf{0,1} ----
        readA(c, 1);
        readB(c, 1, 0);
        if (t + 2 < nt) stagePair(c, 0, t + 2);
        __builtin_amdgcn_s_barrier();
        MMA(0);
        __builtin_amdgcn_s_barrier();
        __builtin_amdgcn_sched_barrier(0);
        // ---- P4: ks1, nf{2,3} ----
        readB(c, 1, 1);
        __builtin_amdgcn_s_barrier();
        MMA(1);
        if (t + 2 < nt) { asm volatile("s_waitcnt vmcnt(4)" ::: "memory"); }
        else            { asm volatile("s_waitcnt vmcnt(0)" ::: "memory"); }
        __builtin_amdgcn_s_barrier();
        __builtin_amdgcn_sched_barrier(0);
    }

    char* Cb = (char*)Cv + (long)z * sC * (CBF16 ? 2 : 4);
    #pragma unroll
    for (int mf = 0; mf < 8; ++mf) {
        #pragma unroll
        for (int nf = 0; nf < 4; ++nf) {
            const long col = ccol0 + wn * 64 + nf * 16 + (lane & 15);
            float bval = 0.f;
            if (HASBIAS) bval = bias[col];
            #pragma unroll
            for (int rr = 0; rr < 4; ++rr) {
                const long row = crow0 + wm * 128 + mf * 16 + ((lane >> 4) << 2) + rr;
                float v = acc[mf][nf][rr] * scale + bval;
                if (RELU) v = fmaxf(v, 0.f);
                const long idx = TRANSC ? (col * (long)ldc + row) : (row * (long)ldc + col);
                if (CBF16) ((u16*)Cb)[idx] = f32_to_bf16(v);
                else       ((float*)Cb)[idx] = v;
            }
        }
    }
}

// ------------------------------------------------------------------
// Proven round-1 128x128 GEMM (kept for scores / PV)
// ------------------------------------------------------------------
template<bool RELU, bool CBF16, bool TRANSC, bool HASBIAS>
__global__ __launch_bounds__(256, 2)
void gemm_bt(const u16* __restrict__ A, const u16* __restrict__ Bt,
             void* __restrict__ Cv, const float* __restrict__ bias,
             int K, int lda, int ldb, int ldc, float scale,
             long sA, long sB, long sC)
{
    __shared__ __attribute__((aligned(16))) u16 As[128 * 64];
    __shared__ __attribute__((aligned(16))) u16 Bs[128 * 64];
    const int z = blockIdx.z;
    const u16* Ab = A + (long)z * sA;
    const u16* Bb = Bt + (long)z * sB;
    const long crow0 = (long)blockIdx.x * 128;
    const long ccol0 = (long)blockIdx.y * 128;
    const int tid = threadIdx.x;
    const int lane = tid & 63;
    const int wv = tid >> 6;
    const int wm = wv >> 1, wn = wv & 1;

    f32x4 acc[4][4] = {};

    const int srow = (wv << 3) + (lane >> 3);
    const int sc8 = lane & 7;

    for (int k0 = 0; k0 < K; k0 += 64) {
        __syncthreads();
        #pragma unroll
        for (int i = 0; i < 4; ++i) {
            const int r = i * 32 + srow;
            const int c8 = sc8 ^ (r & 7);
            const u16* ga = Ab + (crow0 + r) * (long)lda + k0 + c8 * 8;
            const u16* gb = Bb + (ccol0 + r) * (long)ldb + k0 + c8 * 8;
            __builtin_amdgcn_global_load_lds(
                (__attribute__((address_space(1))) void*)ga,
                (__attribute__((address_space(3))) void*)(&As[(i * 32 + wv * 8) * 64]),
                16, 0, 0);
            __builtin_amdgcn_global_load_lds(
                (__attribute__((address_space(1))) void*)gb,
                (__attribute__((address_space(3))) void*)(&Bs[(i * 32 + wv * 8) * 64]),
                16, 0, 0);
        }
        __syncthreads();

        #pragma unroll
        for (int ks = 0; ks < 2; ++ks) {
            short8 af[4], bfr[4];
            const int kg = ks * 4 + (lane >> 4);
            #pragma unroll
            for (int mf = 0; mf < 4; ++mf) {
                const int r = wm * 64 + mf * 16 + (lane & 15);
                af[mf] = *(const short8*)&As[r * 64 + ((kg ^ (r & 7)) << 3)];
            }
            #pragma unroll
            for (int nf = 0; nf < 4; ++nf) {
                const int r = wn * 64 + nf * 16 + (lane & 15);
                bfr[nf] = *(const short8*)&Bs[r * 64 + ((kg ^ (r & 7)) << 3)];
            }
            #pragma unroll
            for (int mf = 0; mf < 4; ++mf)
                #pragma unroll
                for (int nf = 0; nf < 4; ++nf)
                    acc[mf][nf] = __builtin_amdgcn_mfma_f32_16x16x32_bf16(
                        af[mf], bfr[nf], acc[mf][nf], 0, 0, 0);
        }
    }

    char* Cb = (char*)Cv + (long)z * sC * (CBF16 ? 2 : 4);
    #pragma unroll
    for (int mf = 0; mf < 4; ++mf) {
        #pragma unroll
        for (int nf = 0; nf < 4; ++nf) {
            const long col = ccol0 + wn * 64 + nf * 16 + (lane & 15);
            float bval = 0.f;
            if (HASBIAS) bval = bias[col];
            #pragma unroll
            for (int rr = 0; rr < 4; ++rr) {
                const long row = crow0 + wm * 64 + mf * 16 + ((lane >> 4) << 2) + rr;
                float v = acc[mf][nf][rr] * scale + bval;
                if (RELU) v = fmaxf(v, 0.f);
                const long idx = TRANSC ? (col * (long)ldc + row) : (row * (long)ldc + col);
                if (CBF16) ((u16*)Cb)[idx] = f32_to_bf16(v);
                else       ((float*)Cb)[idx] = v;
            }
        }
    }
}

// ----- softmax over rows of 512, in place: f32 row -> bf16 packed at row start -----
__global__ __launch_bounds__(256) void softmax_inplace(float* __restrict__ sc) {
    const int row = blockIdx.x * 4 + (threadIdx.x >> 6);
    const int lane = threadIdx.x & 63;
    float* r = sc + (long)row * 512;
    const float4 a = ((const float4*)r)[lane * 2];
    const float4 b = ((const float4*)r)[lane * 2 + 1];
    float e[8] = {a.x, a.y, a.z, a.w, b.x, b.y, b.z, b.w};
    float m = e[0];
    #pragma unroll
    for (int j = 1; j < 8; ++j) m = fmaxf(m, e[j]);
    #pragma unroll
    for (int o = 32; o; o >>= 1) m = fmaxf(m, __shfl_xor(m, o));
    float s = 0.f;
    #pragma unroll
    for (int j = 0; j < 8; ++j) { e[j] = __expf(e[j] - m); s += e[j]; }
    #pragma unroll
    for (int o = 32; o; o >>= 1) s += __shfl_xor(s, o);
    const float inv = 1.f / s;
    uint4 pk;
    pk.x = (unsigned)f32_to_bf16(e[0] * inv) | ((unsigned)f32_to_bf16(e[1] * inv) << 16);
    pk.y = (unsigned)f32_to_bf16(e[2] * inv) | ((unsigned)f32_to_bf16(e[3] * inv) << 16);
    pk.z = (unsigned)f32_to_bf16(e[4] * inv) | ((unsigned)f32_to_bf16(e[5] * inv) << 16);
    pk.w = (unsigned)f32_to_bf16(e[6] * inv) | ((unsigned)f32_to_bf16(e[7] * inv) << 16);
    ((uint4*)r)[lane] = pk;
}

// ----- per-head FC partial -----
__global__ __launch_bounds__(256) void reduce_head(const float* __restrict__ outh,
                                                   const float* __restrict__ fcw,
                                                   float* __restrict__ part, int h) {
    const int b = blockIdx.x, tid = threadIdx.x;
    const float* ob = outh + (long)b * 512 * 128;
    const float* w0 = fcw + (long)h * 36;
    const float* w1 = fcw + 147456 + (long)h * 36;
    float a0 = 0.f, a1 = 0.f;
    for (int i = tid; i < 512 * 36; i += 256) {
        const int s = i / 36, v = i - s * 36;
        const float f = ob[s * 128 + v];
        a0 += f * w0[(long)s * 288 + v];
        a1 += f * w1[(long)s * 288 + v];
    }
    __shared__ float r0[256], r1[256];
    r0[tid] = a0; r1[tid] = a1;
    __syncthreads();
    for (int o = 128; o; o >>= 1) {
        if (tid < o) { r0[tid] += r0[tid + o]; r1[tid] += r1[tid + o]; }
        __syncthreads();
    }
    if (tid == 0) { part[(h * 32 + b) * 2] = r0[0]; part[(h * 32 + b) * 2 + 1] = r1[0]; }
}

// ----- final: logits -> sigmoid -> log_softmax -----
__global__ void final_k(const float* __restrict__ part, const float* __restrict__ fcb,
                        float* __restrict__ out) {
    const int b = threadIdx.x;
    if (b >= 32) return;
    float l0 = fcb[0], l1 = fcb[1];
    #pragma unroll
    for (int h = 0; h < 8; ++h) { l0 += part[(h * 32 + b) * 2]; l1 += part[(h * 32 + b) * 2 + 1]; }
    const float s0 = 1.f / (1.f + expf(-l0));
    const float s1 = 1.f / (1.f + expf(-l1));
    const float mm = fmaxf(s0, s1);
    const float lse = mm + logf(expf(s0 - mm) + expf(s1 - mm));
    out[b * 2] = s0 - lse; out[b * 2 + 1] = s1 - lse;
    out[64 + b * 2] = s0;  out[64 + b * 2 + 1] = s1;
}

extern "C" void kernel_launch(void* const* d_in, const int* in_sizes, int n_in,
                              void* d_out, int out_size, void* d_ws, size_t ws_size,
                              hipStream_t stream) {
    (void)in_sizes; (void)n_in;
    const int*   tokens = (const int*)  d_in[0];
    const float* emb    = (const float*)d_in[1];
    const float* Wq     = (const float*)d_in[2];
    const float* bq     = (const float*)d_in[3];
    const float* Wk     = (const float*)d_in[4];
    const float* bk     = (const float*)d_in[5];
    const float* Wv     = (const float*)d_in[6];
    const float* bv     = (const float*)d_in[7];
    const float* fcw    = (const float*)d_in[8];
    const float* fcb    = (const float*)d_in[9];
    float* out = (float*)d_out;

    char* wsp = (char*)d_ws;
    size_t need = 0;
    auto alloc = [&](size_t bytes) {
        char* p = wsp + need;
        need += (bytes + 255) & ~(size_t)255;
        return p;
    };
    u16*   xb     = (u16*)  alloc(16384L * 1024 * 2);   // embedded tokens bf16
    u16*   WqkT   = (u16*)  alloc(8L * 2048 * 1024 * 2);// stacked Wq/Wk transposed bf16
    u16*   WvT    = (u16*)  alloc(8L * 128 * 1024 * 2); // Wv transposed, padded
    float* bqk    = (float*)alloc(8L * 2048 * 4);
    float* bvp    = (float*)alloc(8L * 128 * 4);
    u16*   QK     = (u16*)  alloc(16384L * 2048 * 2);   // per-head [Q|K] bf16
    u16*   Vt     = (u16*)  alloc(1024L * 16384 * 2);   // all-head V^T bf16 [h*128+v][b*s]
    float* scores = (float*)alloc(32L * 512 * 512 * 4); // per-head scores f32 / attn bf16
    float* outh   = (float*)alloc(16384L * 128 * 4);    // per-head attention out f32
    float* part   = (float*)alloc(8L * 32 * 2 * 4);
    if (ws_size < need) {
        hipMemsetAsync(d_out, 0, (size_t)out_size * 4, stream);
        return;
    }

    embed_cast<<<16384, 256, 0, stream>>>(tokens, emb, xb);
    pad_bv<<<4, 256, 0, stream>>>(bv, bvp);
    stack_bias<<<64, 256, 0, stream>>>(bq, bk, bqk);
    transpose_qk<<<dim3(32, 32, 16), dim3(32, 8), 0, stream>>>(Wq, Wk, WqkT);
    transpose_v<<<dim3(32, 4, 8), dim3(32, 8), 0, stream>>>(Wv, WvT);

    // all-head V projection: Vt[n][m] = relu(xb @ WvT^T + bvp), transposed store
    gemm8<true, true, true, true><<<dim3(64, 4, 1), 512, 0, stream>>>(
        xb, WvT, Vt, bvp, 1024, 1024, 1024, 16384, 1.f, 0, 0, 0);

    for (int h = 0; h < 8; ++h) {
        // stacked Q|K projection: QK = relu(xb @ WqkT[h]^T + bqk[h])  [16384][2048]
        gemm8<true, true, false, true><<<dim3(64, 8, 1), 512, 0, stream>>>(
            xb, WqkT + (long)h * 2048 * 1024, QK, bqk + h * 2048,
            1024, 1024, 1024, 2048, 1.f, 0, 0, 0);
        // scores[z] = (Q[z] @ K[z]^T) / 32   f32 [512][512], z = batch
        gemm_bt<false, false, false, false><<<dim3(4, 4, 32), 256, 0, stream>>>(
            QK, QK + 1024, scores, nullptr, 1024, 2048, 2048, 512, 0.03125f,
            512L * 2048, 512L * 2048, 512L * 512);
        softmax_inplace<<<4096, 256, 0, stream>>>(scores);
        // outh[z] = attn[z] @ Vt[h-block, z-cols]^T   f32 [512][128]
        gemm_bt<false, false, false, false><<<dim3(4, 1, 32), 256, 0, stream>>>(
            (const u16*)scores, Vt + (long)h * 128 * 16384, outh, nullptr,
            512, 1024, 16384, 128, 1.f, 512L * 1024, 512, 512L * 128);
        reduce_head<<<32, 256, 0, stream>>>(outh, fcw, part, h);
    }
    final_k<<<1, 64, 0, stream>>>(part, fcb, out);
}

// Round 3
// 1102.109 us; speedup vs baseline: 1.3597x; 1.2655x over previous
//
#include <hip/hip_runtime.h>
#include <cstdint>

typedef unsigned short u16;
typedef __attribute__((ext_vector_type(8))) short short8;  // 8 bf16 (4 VGPRs)
typedef __attribute__((ext_vector_type(4))) float f32x4;

__device__ __forceinline__ u16 f32_to_bf16(float f) {
    unsigned u = __builtin_bit_cast(unsigned, f);
    u += 0x7FFFu + ((u >> 16) & 1u);   // RNE
    return (u16)(u >> 16);
}

// ---------------- embed lookup + bf16 cast: xb[b*512+s][e] ----------------
__global__ __launch_bounds__(256) void embed_cast(const int* __restrict__ tok,
                                                  const float* __restrict__ emb,
                                                  u16* __restrict__ xb) {
    const int i = blockIdx.x;                 // 0..16383 token index
    const long t = tok[i];
    const float4 f = ((const float4*)(emb + t * 1024))[threadIdx.x];
    unsigned lo = (unsigned)f32_to_bf16(f.x) | ((unsigned)f32_to_bf16(f.y) << 16);
    unsigned hi = (unsigned)f32_to_bf16(f.z) | ((unsigned)f32_to_bf16(f.w) << 16);
    ((uint2*)(xb + (long)i * 1024))[threadIdx.x] = make_uint2(lo, hi);
}

// ------ Wq/Wk [h][1024][1024] f32 -> WqkT [h][2048][1024] bf16 ------
__global__ __launch_bounds__(256) void transpose_qk(const float* __restrict__ Wq,
                                                    const float* __restrict__ Wk,
                                                    u16* __restrict__ WqkT) {
    const int z = blockIdx.z;                 // h*2 + m
    const int h = z >> 1, m = z & 1;
    const float* W = (m ? Wk : Wq) + (long)h * 1048576;
    u16* out = WqkT + (long)z * 1048576;
    __shared__ float tt[32][33];
    const int kb = blockIdx.x * 32, nb = blockIdx.y * 32;
    const int tx = threadIdx.x, ty = threadIdx.y;   // 32 x 8
    #pragma unroll
    for (int j = 0; j < 32; j += 8)
        tt[ty + j][tx] = W[(long)(kb + ty + j) * 1024 + nb + tx];
    __syncthreads();
    #pragma unroll
    for (int j = 0; j < 32; j += 8)
        out[(long)(nb + ty + j) * 1024 + kb + tx] = f32_to_bf16(tt[tx][ty + j]);
}

// ------ Wv [h][1024][36] f32 -> WvT [h*128 + v][1024] bf16, zero-pad v>=36 ------
__global__ __launch_bounds__(256) void transpose_v(const float* __restrict__ Wv,
                                                   u16* __restrict__ WvT) {
    const int h = blockIdx.z;
    const float* W = Wv + (long)h * 1024 * 36;
    u16* out = WvT + (long)h * 128 * 1024;
    __shared__ float tt[32][33];
    const int kb = blockIdx.x * 32, nb = blockIdx.y * 32;   // nb in 0..96
    const int tx = threadIdx.x, ty = threadIdx.y;
    #pragma unroll
    for (int j = 0; j < 32; j += 8) {
        const int n = nb + tx;
        tt[ty + j][tx] = (n < 36) ? W[(long)(kb + ty + j) * 36 + n] : 0.f;
    }
    __syncthreads();
    #pragma unroll
    for (int j = 0; j < 32; j += 8)
        out[(long)(nb + ty + j) * 1024 + kb + tx] = f32_to_bf16(tt[tx][ty + j]);
}

// ---------------- bias stack: bqk[h][2048] = [bq[h] | bk[h]] ----------------
__global__ void stack_bias(const float* __restrict__ bq, const float* __restrict__ bk,
                           float* __restrict__ bqk) {
    const int i = blockIdx.x * 256 + threadIdx.x;   // < 16384
    const int h = i >> 11, c = i & 2047;
    bqk[i] = (c < 1024) ? bq[h * 1024 + c] : bk[h * 1024 + c - 1024];
}

// ---------------- pad bv [8][36] -> bvp [8][128] ----------------
__global__ void pad_bv(const float* __restrict__ bv, float* __restrict__ bvp) {
    int i = blockIdx.x * 256 + threadIdx.x;   // 0..1023
    int h = i >> 7, n = i & 127;
    bvp[i] = (n < 36) ? bv[h * 36 + n] : 0.f;
}

// ==================================================================
// 8-phase 256x256 GEMM (T1+T2+T3+T4+T5), BK=64, 8 waves (2Mx4N), 512 thr.
// LDS regions: [buf][khalf][op][256 rows][32 cols] bf16 = 128 KiB.
// Swizzle (both sides): 16B-chunk ^= (row>>1)&3.
//   Quarter-wave residues (4r + ((r>>1)&3)) mod 8 cover all 8 bank-groups
//   exactly twice -> free 2-way only (m136).
// Refill: P1 issue (c^1).k1 <- t+1 ; P3 issue (c).k0 <- t+2 ; P4 vmcnt(4).
// Requires nt >= 2, gridDim.x == 64, gridDim.x*gridDim.y % 8 == 0.
// ==================================================================
template<bool RELU, bool CBF16, bool TRANSC, bool HASBIAS>
__global__ __launch_bounds__(512, 2)
void gemm8(const u16* __restrict__ A, const u16* __restrict__ Bt,
           void* __restrict__ Cv, const float* __restrict__ bias,
           int K, int lda, int ldb, int ldc, float scale,
           long sA, long sB, long sC)
{
    __shared__ __attribute__((aligned(16))) u16 lds[2][2][2][256 * 32];
    const int z = blockIdx.z;
    const u16* Ab = A + (long)z * sA;
    const u16* Bb = Bt + (long)z * sB;
    // T1: bijective XCD swizzle over flattened 2D grid (gridDim.x hardcoded 64)
    const int nwg = 64 * gridDim.y;
    int flat = blockIdx.y * 64 + blockIdx.x;
    flat = (flat & 7) * (nwg >> 3) + (flat >> 3);
    const long crow0 = (long)(flat & 63) * 256;
    const long ccol0 = (long)(flat >> 6) * 256;
    const int tid = threadIdx.x;
    const int lane = tid & 63;
    const int wv = tid >> 6;          // 0..7
    const int wm = wv >> 2;           // 0..1
    const int wn = wv & 3;            // 0..3
    const int nt = K >> 6;

    const int srow4 = lane >> 2;      // 0..15
    const int schunk = lane & 3;

    auto stagePair = [&](int buf, int kh, long t) {   // 4 loads/thread: A+B of one k-half
        const long kbase = t * 64 + kh * 32;
        #pragma unroll
        for (int j = 0; j < 2; ++j) {
            const int row = j * 128 + wv * 16 + srow4;
            const int c = schunk ^ ((row >> 1) & 3);   // pre-swizzled global source
            const u16* ga = Ab + (crow0 + row) * (long)lda + kbase + c * 8;
            const u16* gb = Bb + (ccol0 + row) * (long)ldb + kbase + c * 8;
            __builtin_amdgcn_global_load_lds(
                (__attribute__((address_space(1))) void*)ga,
                (__attribute__((address_space(3))) void*)(&lds[buf][kh][0][(j * 128 + wv * 16) * 32]),
                16, 0, 0);
            __builtin_amdgcn_global_load_lds(
                (__attribute__((address_space(1))) void*)gb,
                (__attribute__((address_space(3))) void*)(&lds[buf][kh][1][(j * 128 + wv * 16) * 32]),
                16, 0, 0);
        }
    };

    f32x4 acc[8][4] = {};
    short8 af[8], bf2[2];

    auto readA = [&](int buf, int ks) {
        #pragma unroll
        for (int mf = 0; mf < 8; ++mf) {
            const int row = wm * 128 + mf * 16 + (lane & 15);
            af[mf] = *(const short8*)&lds[buf][ks][0][row * 32 + (((lane >> 4) ^ ((row >> 1) & 3)) << 3)];
        }
    };
    auto readB = [&](int buf, int ks, int nh) {
        #pragma unroll
        for (int i = 0; i < 2; ++i) {
            const int row = wn * 64 + (nh * 2 + i) * 16 + (lane & 15);
            bf2[i] = *(const short8*)&lds[buf][ks][1][row * 32 + (((lane >> 4) ^ ((row >> 1) & 3)) << 3)];
        }
    };
    auto MMA = [&](int nh) {
        __builtin_amdgcn_s_setprio(1);
        #pragma unroll
        for (int mf = 0; mf < 8; ++mf) {
            acc[mf][nh * 2]     = __builtin_amdgcn_mfma_f32_16x16x32_bf16(af[mf], bf2[0], acc[mf][nh * 2], 0, 0, 0);
            acc[mf][nh * 2 + 1] = __builtin_amdgcn_mfma_f32_16x16x32_bf16(af[mf], bf2[1], acc[mf][nh * 2 + 1], 0, 0, 0);
        }
        __builtin_amdgcn_s_setprio(0);
    };

    // prologue: tile0 (both halves) + tile1.k0 = 12 loads; wait all but newest 4
    stagePair(0, 0, 0);
    stagePair(0, 1, 0);
    stagePair(1, 0, 1);
    asm volatile("s_waitcnt vmcnt(4)" ::: "memory");
    __builtin_amdgcn_s_barrier();
    __builtin_amdgcn_sched_barrier(0);

    for (long t = 0; t < nt; ++t) {
        const int c = (int)(t & 1);
        // ---- P1: ks0, nf{0,1} ----
        readA(c, 0);
        readB(c, 0, 0);
        if (t + 1 < nt) stagePair(c ^ 1, 1, t + 1);
        __builtin_amdgcn_s_barrier();
        MMA(0);
        __builtin_amdgcn_s_barrier();
        __builtin_amdgcn_sched_barrier(0);
        // ---- P2: ks0, nf{2,3} ----
        readB(c, 0, 1);
        __builtin_amdgcn_s_barrier();
        MMA(1);
        __builtin_amdgcn_s_barrier();
        __builtin_amdgcn_sched_barrier(0);
        // ---- P3: ks1, nf{0,1} ----
        readA(c, 1);
        readB(c, 1, 0);
        if (t + 2 < nt) stagePair(c, 0, t + 2);
        __builtin_amdgcn_s_barrier();
        MMA(0);
        __builtin_amdgcn_s_barrier();
        __builtin_amdgcn_sched_barrier(0);
        // ---- P4: ks1, nf{2,3} ----
        readB(c, 1, 1);
        __builtin_amdgcn_s_barrier();
        MMA(1);
        if (t + 2 < nt) { asm volatile("s_waitcnt vmcnt(4)" ::: "memory"); }
        else            { asm volatile("s_waitcnt vmcnt(0)" ::: "memory"); }
        __builtin_amdgcn_s_barrier();
        __builtin_amdgcn_sched_barrier(0);
    }

    char* Cb = (char*)Cv + (long)z * sC * (CBF16 ? 2 : 4);
    #pragma unroll
    for (int mf = 0; mf < 8; ++mf) {
        #pragma unroll
        for (int nf = 0; nf < 4; ++nf) {
            const long col = ccol0 + wn * 64 + nf * 16 + (lane & 15);
            float bval = 0.f;
            if (HASBIAS) bval = bias[col];
            #pragma unroll
            for (int rr = 0; rr < 4; ++rr) {
                const long row = crow0 + wm * 128 + mf * 16 + ((lane >> 4) << 2) + rr;
                float v = acc[mf][nf][rr] * scale + bval;
                if (RELU) v = fmaxf(v, 0.f);
                const long idx = TRANSC ? (col * (long)ldc + row) : (row * (long)ldc + col);
                if (CBF16) ((u16*)Cb)[idx] = f32_to_bf16(v);
                else       ((float*)Cb)[idx] = v;
            }
        }
    }
}

// ------------------------------------------------------------------
// Proven 128x128 GEMM (kept for scores); 128B rows -> slot%8 = chunk
// directly, so chunk^=(r&7) is already conflict-free.
// ------------------------------------------------------------------
template<bool RELU, bool CBF16, bool TRANSC, bool HASBIAS>
__global__ __launch_bounds__(256, 2)
void gemm_bt(const u16* __restrict__ A, const u16* __restrict__ Bt,
             void* __restrict__ Cv, const float* __restrict__ bias,
             int K, int lda, int ldb, int ldc, float scale,
             long sA, long sB, long sC)
{
    __shared__ __attribute__((aligned(16))) u16 As[128 * 64];
    __shared__ __attribute__((aligned(16))) u16 Bs[128 * 64];
    const int z = blockIdx.z;
    const u16* Ab = A + (long)z * sA;
    const u16* Bb = Bt + (long)z * sB;
    const long crow0 = (long)blockIdx.x * 128;
    const long ccol0 = (long)blockIdx.y * 128;
    const int tid = threadIdx.x;
    const int lane = tid & 63;
    const int wv = tid >> 6;
    const int wm = wv >> 1, wn = wv & 1;

    f32x4 acc[4][4] = {};

    const int srow = (wv << 3) + (lane >> 3);
    const int sc8 = lane & 7;

    for (int k0 = 0; k0 < K; k0 += 64) {
        __syncthreads();
        #pragma unroll
        for (int i = 0; i < 4; ++i) {
            const int r = i * 32 + srow;
            const int c8 = sc8 ^ (r & 7);
            const u16* ga = Ab + (crow0 + r) * (long)lda + k0 + c8 * 8;
            const u16* gb = Bb + (ccol0 + r) * (long)ldb + k0 + c8 * 8;
            __builtin_amdgcn_global_load_lds(
                (__attribute__((address_space(1))) void*)ga,
                (__attribute__((address_space(3))) void*)(&As[(i * 32 + wv * 8) * 64]),
                16, 0, 0);
            __builtin_amdgcn_global_load_lds(
                (__attribute__((address_space(1))) void*)gb,
                (__attribute__((address_space(3))) void*)(&Bs[(i * 32 + wv * 8) * 64]),
                16, 0, 0);
        }
        __syncthreads();

        #pragma unroll
        for (int ks = 0; ks < 2; ++ks) {
            short8 af[4], bfr[4];
            const int kg = ks * 4 + (lane >> 4);
            #pragma unroll
            for (int mf = 0; mf < 4; ++mf) {
                const int r = wm * 64 + mf * 16 + (lane & 15);
                af[mf] = *(const short8*)&As[r * 64 + ((kg ^ (r & 7)) << 3)];
            }
            #pragma unroll
            for (int nf = 0; nf < 4; ++nf) {
                const int r = wn * 64 + nf * 16 + (lane & 15);
                bfr[nf] = *(const short8*)&Bs[r * 64 + ((kg ^ (r & 7)) << 3)];
            }
            #pragma unroll
            for (int mf = 0; mf < 4; ++mf)
                #pragma unroll
                for (int nf = 0; nf < 4; ++nf)
                    acc[mf][nf] = __builtin_amdgcn_mfma_f32_16x16x32_bf16(
                        af[mf], bfr[nf], acc[mf][nf], 0, 0, 0);
        }
    }

    char* Cb = (char*)Cv + (long)z * sC * (CBF16 ? 2 : 4);
    #pragma unroll
    for (int mf = 0; mf < 4; ++mf) {
        #pragma unroll
        for (int nf = 0; nf < 4; ++nf) {
            const long col = ccol0 + wn * 64 + nf * 16 + (lane & 15);
            float bval = 0.f;
            if (HASBIAS) bval = bias[col];
            #pragma unroll
            for (int rr = 0; rr < 4; ++rr) {
                const long row = crow0 + wm * 64 + mf * 16 + ((lane >> 4) << 2) + rr;
                float v = acc[mf][nf][rr] * scale + bval;
                if (RELU) v = fmaxf(v, 0.f);
                const long idx = TRANSC ? (col * (long)ldc + row) : (row * (long)ldc + col);
                if (CBF16) ((u16*)Cb)[idx] = f32_to_bf16(v);
                else       ((float*)Cb)[idx] = v;
            }
        }
    }
}

// ----- softmax over rows of 512, in place: f32 row -> bf16 packed at row start -----
__global__ __launch_bounds__(256) void softmax_inplace(float* __restrict__ sc) {
    const int row = blockIdx.x * 4 + (threadIdx.x >> 6);
    const int lane = threadIdx.x & 63;
    float* r = sc + (long)row * 512;
    const float4 a = ((const float4*)r)[lane * 2];
    const float4 b = ((const float4*)r)[lane * 2 + 1];
    float e[8] = {a.x, a.y, a.z, a.w, b.x, b.y, b.z, b.w};
    float m = e[0];
    #pragma unroll
    for (int j = 1; j < 8; ++j) m = fmaxf(m, e[j]);
    #pragma unroll
    for (int o = 32; o; o >>= 1) m = fmaxf(m, __shfl_xor(m, o));
    float s = 0.f;
    #pragma unroll
    for (int j = 0; j < 8; ++j) { e[j] = __expf(e[j] - m); s += e[j]; }
    #pragma unroll
    for (int o = 32; o; o >>= 1) s += __shfl_xor(s, o);
    const float inv = 1.f / s;
    uint4 pk;
    pk.x = (unsigned)f32_to_bf16(e[0] * inv) | ((unsigned)f32_to_bf16(e[1] * inv) << 16);
    pk.y = (unsigned)f32_to_bf16(e[2] * inv) | ((unsigned)f32_to_bf16(e[3] * inv) << 16);
    pk.z = (unsigned)f32_to_bf16(e[4] * inv) | ((unsigned)f32_to_bf16(e[5] * inv) << 16);
    pk.w = (unsigned)f32_to_bf16(e[6] * inv) | ((unsigned)f32_to_bf16(e[7] * inv) << 16);
    ((uint4*)r)[lane] = pk;
}

// ==================================================================
// PV + fused FC: block (mb, kb, z) computes partial out[s in mb-range][v]
// over attn-cols kb*128..+128, dots with fcw slice, writes 2 partials.
// part2 layout: [h][z][mb][kb][2]. Deterministic (no atomics).
// ==================================================================
__global__ __launch_bounds__(256, 2)
void pv_fc(const u16* __restrict__ attn, const u16* __restrict__ Vt,
           const float* __restrict__ fcw, float* __restrict__ part2, int h)
{
    __shared__ __attribute__((aligned(16))) u16 As[128 * 64];
    __shared__ __attribute__((aligned(16))) u16 Bs[128 * 64];
    const int mb = blockIdx.x, kb = blockIdx.y, z = blockIdx.z;
    const u16* Ab = attn + (long)z * 512 * 1024 + (long)kb * 128;  // lda(u16)=1024 (f32 row stride)
    const u16* Bb = Vt + (long)h * 128 * 16384 + (long)z * 512 + (long)kb * 128;  // ldb=16384
    const long crow0 = (long)mb * 128;
    const int tid = threadIdx.x, lane = tid & 63, wv = tid >> 6;
    const int wm = wv >> 1, wn = wv & 1;

    f32x4 acc[4][4] = {};
    const int srow = (wv << 3) + (lane >> 3);
    const int sc8 = lane & 7;

    #pragma unroll
    for (int k0 = 0; k0 < 128; k0 += 64) {
        __syncthreads();
        #pragma unroll
        for (int i = 0; i < 4; ++i) {
            const int r = i * 32 + srow;
            const int c8 = sc8 ^ (r & 7);
            const u16* ga = Ab + (crow0 + r) * 1024L + k0 + c8 * 8;
            const u16* gb = Bb + (long)r * 16384 + k0 + c8 * 8;
            __builtin_amdgcn_global_load_lds(
                (__attribute__((address_space(1))) void*)ga,
                (__attribute__((address_space(3))) void*)(&As[(i * 32 + wv * 8) * 64]),
                16, 0, 0);
            __builtin_amdgcn_global_load_lds(
                (__attribute__((address_space(1))) void*)gb,
                (__attribute__((address_space(3))) void*)(&Bs[(i * 32 + wv * 8) * 64]),
                16, 0, 0);
        }
        __syncthreads();

        #pragma unroll
        for (int ks = 0; ks < 2; ++ks) {
            short8 af[4], bfr[4];
            const int kg = ks * 4 + (lane >> 4);
            #pragma unroll
            for (int mf = 0; mf < 4; ++mf) {
                const int r = wm * 64 + mf * 16 + (lane & 15);
                af[mf] = *(const short8*)&As[r * 64 + ((kg ^ (r & 7)) << 3)];
            }
            #pragma unroll
            for (int nf = 0; nf < 4; ++nf) {
                const int r = wn * 64 + nf * 16 + (lane & 15);
                bfr[nf] = *(const short8*)&Bs[r * 64 + ((kg ^ (r & 7)) << 3)];
            }
            #pragma unroll
            for (int mf = 0; mf < 4; ++mf)
                #pragma unroll
                for (int nf = 0; nf < 4; ++nf)
                    acc[mf][nf] = __builtin_amdgcn_mfma_f32_16x16x32_bf16(
                        af[mf], bfr[nf], acc[mf][nf], 0, 0, 0);
        }
    }

    // fused FC epilogue: only cols < 36 carry signal (Vt pad rows are zero)
    float c0 = 0.f, c1 = 0.f;
    #pragma unroll
    for (int nf = 0; nf < 4; ++nf) {
        const int col = wn * 64 + nf * 16 + (lane & 15);
        if (col < 36) {
            #pragma unroll
            for (int mf = 0; mf < 4; ++mf) {
                #pragma unroll
                for (int rr = 0; rr < 4; ++rr) {
                    const long row = crow0 + wm * 64 + mf * 16 + ((lane >> 4) << 2) + rr;
                    const float v = acc[mf][nf][rr];
                    const long wi = row * 288 + h * 36 + col;
                    c0 += v * fcw[wi];
                    c1 += v * fcw[147456 + wi];
                }
            }
        }
    }
    #pragma unroll
    for (int o = 32; o; o >>= 1) { c0 += __shfl_xor(c0, o); c1 += __shfl_xor(c1, o); }
    __shared__ float red[8];
    if (lane == 0) { red[wv * 2] = c0; red[wv * 2 + 1] = c1; }
    __syncthreads();
    if (tid == 0) {
        const float s0 = red[0] + red[2] + red[4] + red[6];
        const float s1 = red[1] + red[3] + red[5] + red[7];
        float* p = part2 + (((long)(h * 32 + z) * 4 + mb) * 4 + kb) * 2;
        p[0] = s0; p[1] = s1;
    }
}

// ----- final: logits -> sigmoid -> log_softmax; fixed summation order -----
__global__ void final_k(const float* __restrict__ part2, const float* __restrict__ fcb,
                        float* __restrict__ out) {
    const int b = threadIdx.x;
    if (b >= 32) return;
    float l0 = fcb[0], l1 = fcb[1];
    for (int h = 0; h < 8; ++h)
        #pragma unroll
        for (int mb = 0; mb < 4; ++mb)
            #pragma unroll
            for (int kb = 0; kb < 4; ++kb) {
                const float* p = part2 + (((long)(h * 32 + b) * 4 + mb) * 4 + kb) * 2;
                l0 += p[0]; l1 += p[1];
            }
    const float s0 = 1.f / (1.f + expf(-l0));
    const float s1 = 1.f / (1.f + expf(-l1));
    const float mm = fmaxf(s0, s1);
    const float lse = mm + logf(expf(s0 - mm) + expf(s1 - mm));
    out[b * 2] = s0 - lse; out[b * 2 + 1] = s1 - lse;
    out[64 + b * 2] = s0;  out[64 + b * 2 + 1] = s1;
}

extern "C" void kernel_launch(void* const* d_in, const int* in_sizes, int n_in,
                              void* d_out, int out_size, void* d_ws, size_t ws_size,
                              hipStream_t stream) {
    (void)in_sizes; (void)n_in;
    const int*   tokens = (const int*)  d_in[0];
    const float* emb    = (const float*)d_in[1];
    const float* Wq     = (const float*)d_in[2];
    const float* bq     = (const float*)d_in[3];
    const float* Wk     = (const float*)d_in[4];
    const float* bk     = (const float*)d_in[5];
    const float* Wv     = (const float*)d_in[6];
    const float* bv     = (const float*)d_in[7];
    const float* fcw    = (const float*)d_in[8];
    const float* fcb    = (const float*)d_in[9];
    float* out = (float*)d_out;

    char* wsp = (char*)d_ws;
    size_t need = 0;
    auto alloc = [&](size_t bytes) {
        char* p = wsp + need;
        need += (bytes + 255) & ~(size_t)255;
        return p;
    };
    u16*   xb     = (u16*)  alloc(16384L * 1024 * 2);   // embedded tokens bf16
    u16*   WqkT   = (u16*)  alloc(8L * 2048 * 1024 * 2);// stacked Wq/Wk transposed bf16
    u16*   WvT    = (u16*)  alloc(8L * 128 * 1024 * 2); // Wv transposed, padded
    float* bqk    = (float*)alloc(8L * 2048 * 4);
    float* bvp    = (float*)alloc(8L * 128 * 4);
    u16*   QK     = (u16*)  alloc(16384L * 2048 * 2);   // per-head [Q|K] bf16
    u16*   Vt     = (u16*)  alloc(1024L * 16384 * 2);   // all-head V^T bf16 [h*128+v][b*s]
    float* scores = (float*)alloc(32L * 512 * 512 * 4); // per-head scores f32 / attn bf16
    float* part2  = (float*)alloc(8L * 32 * 4 * 4 * 2 * 4);
    if (ws_size < need) {
        hipMemsetAsync(d_out, 0, (size_t)out_size * 4, stream);
        return;
    }

    embed_cast<<<16384, 256, 0, stream>>>(tokens, emb, xb);
    pad_bv<<<4, 256, 0, stream>>>(bv, bvp);
    stack_bias<<<64, 256, 0, stream>>>(bq, bk, bqk);
    transpose_qk<<<dim3(32, 32, 16), dim3(32, 8), 0, stream>>>(Wq, Wk, WqkT);
    transpose_v<<<dim3(32, 4, 8), dim3(32, 8), 0, stream>>>(Wv, WvT);

    // all-head V projection: Vt[n][m] = relu(xb @ WvT^T + bvp), transposed store
    gemm8<true, true, true, true><<<dim3(64, 4, 1), 512, 0, stream>>>(
        xb, WvT, Vt, bvp, 1024, 1024, 1024, 16384, 1.f, 0, 0, 0);

    for (int h = 0; h < 8; ++h) {
        // stacked Q|K projection: QK = relu(xb @ WqkT[h]^T + bqk[h])  [16384][2048]
        gemm8<true, true, false, true><<<dim3(64, 8, 1), 512, 0, stream>>>(
            xb, WqkT + (long)h * 2048 * 1024, QK, bqk + h * 2048,
            1024, 1024, 1024, 2048, 1.f, 0, 0, 0);
        // scores[z] = (Q[z] @ K[z]^T) / 32   f32 [512][512], z = batch
        gemm_bt<false, false, false, false><<<dim3(4, 4, 32), 256, 0, stream>>>(
            QK, QK + 1024, scores, nullptr, 1024, 2048, 2048, 512, 0.03125f,
            512L * 2048, 512L * 2048, 512L * 512);
        softmax_inplace<<<4096, 256, 0, stream>>>(scores);
        // PV + fused FC partials
        pv_fc<<<dim3(4, 4, 32), 256, 0, stream>>>(
            (const u16*)scores, Vt, fcw, part2, h);
    }
    final_k<<<1, 64, 0, stream>>>(part2, fcb, out);
}

// Round 4
// 1059.368 us; speedup vs baseline: 1.4146x; 1.0403x over previous
//
#include <hip/hip_runtime.h>
#include <cstdint>

typedef unsigned short u16;
typedef __attribute__((ext_vector_type(8))) short short8;  // 8 bf16 (4 VGPRs)
typedef __attribute__((ext_vector_type(4))) float f32x4;

__device__ __forceinline__ u16 f32_to_bf16(float f) {
    unsigned u = __builtin_bit_cast(unsigned, f);
    u += 0x7FFFu + ((u >> 16) & 1u);   // RNE
    return (u16)(u >> 16);
}

// hardware barrier that is also a compiler memory fence (but NOT a full
// scheduling pin like sched_barrier(0) — ALU may still move across)
#define BARF() asm volatile("s_barrier" ::: "memory")

// ---------------- embed lookup + bf16 cast: xb[b*512+s][e] ----------------
__global__ __launch_bounds__(256) void embed_cast(const int* __restrict__ tok,
                                                  const float* __restrict__ emb,
                                                  u16* __restrict__ xb) {
    const int i = blockIdx.x;                 // 0..16383 token index
    const long t = tok[i];
    const float4 f = ((const float4*)(emb + t * 1024))[threadIdx.x];
    unsigned lo = (unsigned)f32_to_bf16(f.x) | ((unsigned)f32_to_bf16(f.y) << 16);
    unsigned hi = (unsigned)f32_to_bf16(f.z) | ((unsigned)f32_to_bf16(f.w) << 16);
    ((uint2*)(xb + (long)i * 1024))[threadIdx.x] = make_uint2(lo, hi);
}

// ------ Wq/Wk [h][1024][1024] f32 -> WqkT [h][2048][1024] bf16 ------
__global__ __launch_bounds__(256) void transpose_qk(const float* __restrict__ Wq,
                                                    const float* __restrict__ Wk,
                                                    u16* __restrict__ WqkT) {
    const int z = blockIdx.z;                 // h*2 + m
    const int h = z >> 1, m = z & 1;
    const float* W = (m ? Wk : Wq) + (long)h * 1048576;
    u16* out = WqkT + (long)z * 1048576;
    __shared__ float tt[32][33];
    const int kb = blockIdx.x * 32, nb = blockIdx.y * 32;
    const int tx = threadIdx.x, ty = threadIdx.y;   // 32 x 8
    #pragma unroll
    for (int j = 0; j < 32; j += 8)
        tt[ty + j][tx] = W[(long)(kb + ty + j) * 1024 + nb + tx];
    __syncthreads();
    #pragma unroll
    for (int j = 0; j < 32; j += 8)
        out[(long)(nb + ty + j) * 1024 + kb + tx] = f32_to_bf16(tt[tx][ty + j]);
}

// ------ Wv [h][1024][36] f32 -> WvT [h*128 + v][1024] bf16, zero-pad v>=36 ------
__global__ __launch_bounds__(256) void transpose_v(const float* __restrict__ Wv,
                                                   u16* __restrict__ WvT) {
    const int h = blockIdx.z;
    const float* W = Wv + (long)h * 1024 * 36;
    u16* out = WvT + (long)h * 128 * 1024;
    __shared__ float tt[32][33];
    const int kb = blockIdx.x * 32, nb = blockIdx.y * 32;   // nb in 0..96
    const int tx = threadIdx.x, ty = threadIdx.y;
    #pragma unroll
    for (int j = 0; j < 32; j += 8) {
        const int n = nb + tx;
        tt[ty + j][tx] = (n < 36) ? W[(long)(kb + ty + j) * 36 + n] : 0.f;
    }
    __syncthreads();
    #pragma unroll
    for (int j = 0; j < 32; j += 8)
        out[(long)(nb + ty + j) * 1024 + kb + tx] = f32_to_bf16(tt[tx][ty + j]);
}

// ---------------- bias stack: bqk[h][2048] = [bq[h] | bk[h]] ----------------
__global__ void stack_bias(const float* __restrict__ bq, const float* __restrict__ bk,
                           float* __restrict__ bqk) {
    const int i = blockIdx.x * 256 + threadIdx.x;   // < 16384
    const int h = i >> 11, c = i & 2047;
    bqk[i] = (c < 1024) ? bq[h * 1024 + c] : bk[h * 1024 + c - 1024];
}

// ---------------- pad bv [8][36] -> bvp [8][128] ----------------
__global__ void pad_bv(const float* __restrict__ bv, float* __restrict__ bvp) {
    int i = blockIdx.x * 256 + threadIdx.x;   // 0..1023
    int h = i >> 7, n = i & 127;
    bvp[i] = (n < 36) ? bv[h * 36 + n] : 0.f;
}

// ==================================================================
// 8-phase 256x256 GEMM (T2+T3+T4+T5), BK=64, 8 waves (2Mx4N), 512 thr.
// LDS regions: [buf][khalf][op][256 rows][32 cols] bf16 = 128 KiB.
// Swizzle (both sides): 16B-chunk ^= (row>>1)&3  (conflict-free, verified r3).
// Refill: P1 issue (c^1).k1 <- t+1 ; P3 issue (c).k0 <- t+2 ; P4 vmcnt(4).
// Barriers are asm s_barrier + "memory" clobber: HW sync + compiler memory
// fence, but NO sched_barrier(0) pin (m141 lesson) — ALU flows across.
// Requires nt >= 2.
// ==================================================================
template<bool RELU, bool CBF16, bool TRANSC, bool HASBIAS>
__global__ __launch_bounds__(512, 2)
void gemm8(const u16* __restrict__ A, const u16* __restrict__ Bt,
           void* __restrict__ Cv, const float* __restrict__ bias,
           int K, int lda, int ldb, int ldc, float scale,
           long sA, long sB, long sC)
{
    __shared__ __attribute__((aligned(16))) u16 lds[2][2][2][256 * 32];
    const int z = blockIdx.z;
    const u16* Ab = A + (long)z * sA;
    const u16* Bb = Bt + (long)z * sB;
    const long crow0 = (long)blockIdx.x * 256;
    const long ccol0 = (long)blockIdx.y * 256;
    const int tid = threadIdx.x;
    const int lane = tid & 63;
    const int wv = tid >> 6;          // 0..7
    const int wm = wv >> 2;           // 0..1
    const int wn = wv & 3;            // 0..3
    const int nt = K >> 6;

    const int srow4 = lane >> 2;      // 0..15
    const int schunk = lane & 3;

    auto stagePair = [&](int buf, int kh, long t) {   // 4 loads/thread: A+B of one k-half
        const long kbase = t * 64 + kh * 32;
        #pragma unroll
        for (int j = 0; j < 2; ++j) {
            const int row = j * 128 + wv * 16 + srow4;
            const int c = schunk ^ ((row >> 1) & 3);   // pre-swizzled global source
            const u16* ga = Ab + (crow0 + row) * (long)lda + kbase + c * 8;
            const u16* gb = Bb + (ccol0 + row) * (long)ldb + kbase + c * 8;
            __builtin_amdgcn_global_load_lds(
                (__attribute__((address_space(1))) void*)ga,
                (__attribute__((address_space(3))) void*)(&lds[buf][kh][0][(j * 128 + wv * 16) * 32]),
                16, 0, 0);
            __builtin_amdgcn_global_load_lds(
                (__attribute__((address_space(1))) void*)gb,
                (__attribute__((address_space(3))) void*)(&lds[buf][kh][1][(j * 128 + wv * 16) * 32]),
                16, 0, 0);
        }
    };

    f32x4 acc[8][4] = {};
    short8 af[8], bf2[2];

    auto readA = [&](int buf, int ks) {
        #pragma unroll
        for (int mf = 0; mf < 8; ++mf) {
            const int row = wm * 128 + mf * 16 + (lane & 15);
            af[mf] = *(const short8*)&lds[buf][ks][0][row * 32 + (((lane >> 4) ^ ((row >> 1) & 3)) << 3)];
        }
    };
    auto readB = [&](int buf, int ks, int nh) {
        #pragma unroll
        for (int i = 0; i < 2; ++i) {
            const int row = wn * 64 + (nh * 2 + i) * 16 + (lane & 15);
            bf2[i] = *(const short8*)&lds[buf][ks][1][row * 32 + (((lane >> 4) ^ ((row >> 1) & 3)) << 3)];
        }
    };
    auto MMA = [&](int nh) {
        __builtin_amdgcn_s_setprio(1);
        #pragma unroll
        for (int mf = 0; mf < 8; ++mf) {
            acc[mf][nh * 2]     = __builtin_amdgcn_mfma_f32_16x16x32_bf16(af[mf], bf2[0], acc[mf][nh * 2], 0, 0, 0);
            acc[mf][nh * 2 + 1] = __builtin_amdgcn_mfma_f32_16x16x32_bf16(af[mf], bf2[1], acc[mf][nh * 2 + 1], 0, 0, 0);
        }
        __builtin_amdgcn_s_setprio(0);
    };

    // prologue: tile0 (both halves) + tile1.k0 = 12 loads; wait all but newest 4
    stagePair(0, 0, 0);
    stagePair(0, 1, 0);
    stagePair(1, 0, 1);
    asm volatile("s_waitcnt vmcnt(4)" ::: "memory");
    BARF();

    for (long t = 0; t < nt; ++t) {
        const int c = (int)(t & 1);
        // ---- P1: ks0, nf{0,1} ----
        readA(c, 0);
        readB(c, 0, 0);
        if (t + 1 < nt) stagePair(c ^ 1, 1, t + 1);
        BARF();
        MMA(0);
        BARF();
        // ---- P2: ks0, nf{2,3} ----
        readB(c, 0, 1);
        BARF();
        MMA(1);
        BARF();
        // ---- P3: ks1, nf{0,1} ----
        readA(c, 1);
        readB(c, 1, 0);
        if (t + 2 < nt) stagePair(c, 0, t + 2);
        BARF();
        MMA(0);
        BARF();
        // ---- P4: ks1, nf{2,3} ----
        readB(c, 1, 1);
        BARF();
        MMA(1);
        if (t + 2 < nt) { asm volatile("s_waitcnt vmcnt(4)" ::: "memory"); }
        else            { asm volatile("s_waitcnt vmcnt(0)" ::: "memory"); }
        BARF();
    }

    char* Cb = (char*)Cv + (long)z * sC * (CBF16 ? 2 : 4);
    #pragma unroll
    for (int mf = 0; mf < 8; ++mf) {
        #pragma unroll
        for (int nf = 0; nf < 4; ++nf) {
            const long col = ccol0 + wn * 64 + nf * 16 + (lane & 15);
            float bval = 0.f;
            if (HASBIAS) bval = bias[col];
            #pragma unroll
            for (int rr = 0; rr < 4; ++rr) {
                const long row = crow0 + wm * 128 + mf * 16 + ((lane >> 4) << 2) + rr;
                float v = acc[mf][nf][rr] * scale + bval;
                if (RELU) v = fmaxf(v, 0.f);
                const long idx = TRANSC ? (col * (long)ldc + row) : (row * (long)ldc + col);
                if (CBF16) ((u16*)Cb)[idx] = f32_to_bf16(v);
                else       ((float*)Cb)[idx] = v;
            }
        }
    }
}

// ------------------------------------------------------------------
// Proven 128x128 GEMM (scores); 4 blocks/CU (32 KiB LDS, 104 VGPR).
// ------------------------------------------------------------------
template<bool RELU, bool CBF16, bool TRANSC, bool HASBIAS>
__global__ __launch_bounds__(256, 4)
void gemm_bt(const u16* __restrict__ A, const u16* __restrict__ Bt,
             void* __restrict__ Cv, const float* __restrict__ bias,
             int K, int lda, int ldb, int ldc, float scale,
             long sA, long sB, long sC)
{
    __shared__ __attribute__((aligned(16))) u16 As[128 * 64];
    __shared__ __attribute__((aligned(16))) u16 Bs[128 * 64];
    const int z = blockIdx.z;
    const u16* Ab = A + (long)z * sA;
    const u16* Bb = Bt + (long)z * sB;
    const long crow0 = (long)blockIdx.x * 128;
    const long ccol0 = (long)blockIdx.y * 128;
    const int tid = threadIdx.x;
    const int lane = tid & 63;
    const int wv = tid >> 6;
    const int wm = wv >> 1, wn = wv & 1;

    f32x4 acc[4][4] = {};

    const int srow = (wv << 3) + (lane >> 3);
    const int sc8 = lane & 7;

    for (int k0 = 0; k0 < K; k0 += 64) {
        __syncthreads();
        #pragma unroll
        for (int i = 0; i < 4; ++i) {
            const int r = i * 32 + srow;
            const int c8 = sc8 ^ (r & 7);
            const u16* ga = Ab + (crow0 + r) * (long)lda + k0 + c8 * 8;
            const u16* gb = Bb + (ccol0 + r) * (long)ldb + k0 + c8 * 8;
            __builtin_amdgcn_global_load_lds(
                (__attribute__((address_space(1))) void*)ga,
                (__attribute__((address_space(3))) void*)(&As[(i * 32 + wv * 8) * 64]),
                16, 0, 0);
            __builtin_amdgcn_global_load_lds(
                (__attribute__((address_space(1))) void*)gb,
                (__attribute__((address_space(3))) void*)(&Bs[(i * 32 + wv * 8) * 64]),
                16, 0, 0);
        }
        __syncthreads();

        #pragma unroll
        for (int ks = 0; ks < 2; ++ks) {
            short8 af[4], bfr[4];
            const int kg = ks * 4 + (lane >> 4);
            #pragma unroll
            for (int mf = 0; mf < 4; ++mf) {
                const int r = wm * 64 + mf * 16 + (lane & 15);
                af[mf] = *(const short8*)&As[r * 64 + ((kg ^ (r & 7)) << 3)];
            }
            #pragma unroll
            for (int nf = 0; nf < 4; ++nf) {
                const int r = wn * 64 + nf * 16 + (lane & 15);
                bfr[nf] = *(const short8*)&Bs[r * 64 + ((kg ^ (r & 7)) << 3)];
            }
            #pragma unroll
            for (int mf = 0; mf < 4; ++mf)
                #pragma unroll
                for (int nf = 0; nf < 4; ++nf)
                    acc[mf][nf] = __builtin_amdgcn_mfma_f32_16x16x32_bf16(
                        af[mf], bfr[nf], acc[mf][nf], 0, 0, 0);
        }
    }

    char* Cb = (char*)Cv + (long)z * sC * (CBF16 ? 2 : 4);
    #pragma unroll
    for (int mf = 0; mf < 4; ++mf) {
        #pragma unroll
        for (int nf = 0; nf < 4; ++nf) {
            const long col = ccol0 + wn * 64 + nf * 16 + (lane & 15);
            float bval = 0.f;
            if (HASBIAS) bval = bias[col];
            #pragma unroll
            for (int rr = 0; rr < 4; ++rr) {
                const long row = crow0 + wm * 64 + mf * 16 + ((lane >> 4) << 2) + rr;
                float v = acc[mf][nf][rr] * scale + bval;
                if (RELU) v = fmaxf(v, 0.f);
                const long idx = TRANSC ? (col * (long)ldc + row) : (row * (long)ldc + col);
                if (CBF16) ((u16*)Cb)[idx] = f32_to_bf16(v);
                else       ((float*)Cb)[idx] = v;
            }
        }
    }
}

// ----- softmax over rows of 512, in place: f32 row -> bf16 packed at row start -----
__global__ __launch_bounds__(256) void softmax_inplace(float* __restrict__ sc) {
    const int row = blockIdx.x * 4 + (threadIdx.x >> 6);
    const int lane = threadIdx.x & 63;
    float* r = sc + (long)row * 512;
    const float4 a = ((const float4*)r)[lane * 2];
    const float4 b = ((const float4*)r)[lane * 2 + 1];
    float e[8] = {a.x, a.y, a.z, a.w, b.x, b.y, b.z, b.w};
    float m = e[0];
    #pragma unroll
    for (int j = 1; j < 8; ++j) m = fmaxf(m, e[j]);
    #pragma unroll
    for (int o = 32; o; o >>= 1) m = fmaxf(m, __shfl_xor(m, o));
    float s = 0.f;
    #pragma unroll
    for (int j = 0; j < 8; ++j) { e[j] = __expf(e[j] - m); s += e[j]; }
    #pragma unroll
    for (int o = 32; o; o >>= 1) s += __shfl_xor(s, o);
    const float inv = 1.f / s;
    uint4 pk;
    pk.x = (unsigned)f32_to_bf16(e[0] * inv) | ((unsigned)f32_to_bf16(e[1] * inv) << 16);
    pk.y = (unsigned)f32_to_bf16(e[2] * inv) | ((unsigned)f32_to_bf16(e[3] * inv) << 16);
    pk.z = (unsigned)f32_to_bf16(e[4] * inv) | ((unsigned)f32_to_bf16(e[5] * inv) << 16);
    pk.w = (unsigned)f32_to_bf16(e[6] * inv) | ((unsigned)f32_to_bf16(e[7] * inv) << 16);
    ((uint4*)r)[lane] = pk;
}

// ==================================================================
// PV + fused FC: block (mb, kb, z) computes partial out[s in mb-range][v]
// over attn-cols kb*128..+128, dots with fcw slice, writes 2 partials.
// part2 layout: [h][z][mb][kb][2]. Deterministic (no atomics).
// ==================================================================
__global__ __launch_bounds__(256, 4)
void pv_fc(const u16* __restrict__ attn, const u16* __restrict__ Vt,
           const float* __restrict__ fcw, float* __restrict__ part2, int h)
{
    __shared__ __attribute__((aligned(16))) u16 As[128 * 64];
    __shared__ __attribute__((aligned(16))) u16 Bs[128 * 64];
    const int mb = blockIdx.x, kb = blockIdx.y, z = blockIdx.z;
    const u16* Ab = attn + (long)z * 512 * 1024 + (long)kb * 128;  // lda(u16)=1024 (f32 row stride)
    const u16* Bb = Vt + (long)h * 128 * 16384 + (long)z * 512 + (long)kb * 128;  // ldb=16384
    const long crow0 = (long)mb * 128;
    const int tid = threadIdx.x, lane = tid & 63, wv = tid >> 6;
    const int wm = wv >> 1, wn = wv & 1;

    f32x4 acc[4][4] = {};
    const int srow = (wv << 3) + (lane >> 3);
    const int sc8 = lane & 7;

    #pragma unroll
    for (int k0 = 0; k0 < 128; k0 += 64) {
        __syncthreads();
        #pragma unroll
        for (int i = 0; i < 4; ++i) {
            const int r = i * 32 + srow;
            const int c8 = sc8 ^ (r & 7);
            const u16* ga = Ab + (crow0 + r) * 1024L + k0 + c8 * 8;
            const u16* gb = Bb + (long)r * 16384 + k0 + c8 * 8;
            __builtin_amdgcn_global_load_lds(
                (__attribute__((address_space(1))) void*)ga,
                (__attribute__((address_space(3))) void*)(&As[(i * 32 + wv * 8) * 64]),
                16, 0, 0);
            __builtin_amdgcn_global_load_lds(
                (__attribute__((address_space(1))) void*)gb,
                (__attribute__((address_space(3))) void*)(&Bs[(i * 32 + wv * 8) * 64]),
                16, 0, 0);
        }
        __syncthreads();

        #pragma unroll
        for (int ks = 0; ks < 2; ++ks) {
            short8 af[4], bfr[4];
            const int kg = ks * 4 + (lane >> 4);
            #pragma unroll
            for (int mf = 0; mf < 4; ++mf) {
                const int r = wm * 64 + mf * 16 + (lane & 15);
                af[mf] = *(const short8*)&As[r * 64 + ((kg ^ (r & 7)) << 3)];
            }
            #pragma unroll
            for (int nf = 0; nf < 4; ++nf) {
                const int r = wn * 64 + nf * 16 + (lane & 15);
                bfr[nf] = *(const short8*)&Bs[r * 64 + ((kg ^ (r & 7)) << 3)];
            }
            #pragma unroll
            for (int mf = 0; mf < 4; ++mf)
                #pragma unroll
                for (int nf = 0; nf < 4; ++nf)
                    acc[mf][nf] = __builtin_amdgcn_mfma_f32_16x16x32_bf16(
                        af[mf], bfr[nf], acc[mf][nf], 0, 0, 0);
        }
    }

    // fused FC epilogue: only cols < 36 carry signal (Vt pad rows are zero)
    float c0 = 0.f, c1 = 0.f;
    #pragma unroll
    for (int nf = 0; nf < 4; ++nf) {
        const int col = wn * 64 + nf * 16 + (lane & 15);
        if (col < 36) {
            #pragma unroll
            for (int mf = 0; mf < 4; ++mf) {
                #pragma unroll
                for (int rr = 0; rr < 4; ++rr) {
                    const long row = crow0 + wm * 64 + mf * 16 + ((lane >> 4) << 2) + rr;
                    const float v = acc[mf][nf][rr];
                    const long wi = row * 288 + h * 36 + col;
                    c0 += v * fcw[wi];
                    c1 += v * fcw[147456 + wi];
                }
            }
        }
    }
    #pragma unroll
    for (int o = 32; o; o >>= 1) { c0 += __shfl_xor(c0, o); c1 += __shfl_xor(c1, o); }
    __shared__ float red[8];
    if (lane == 0) { red[wv * 2] = c0; red[wv * 2 + 1] = c1; }
    __syncthreads();
    if (tid == 0) {
        const float s0 = red[0] + red[2] + red[4] + red[6];
        const float s1 = red[1] + red[3] + red[5] + red[7];
        float* p = part2 + (((long)(h * 32 + z) * 4 + mb) * 4 + kb) * 2;
        p[0] = s0; p[1] = s1;
    }
}

// ----- final: logits -> sigmoid -> log_softmax; fixed summation order -----
__global__ void final_k(const float* __restrict__ part2, const float* __restrict__ fcb,
                        float* __restrict__ out) {
    const int b = threadIdx.x;
    if (b >= 32) return;
    float l0 = fcb[0], l1 = fcb[1];
    for (int h = 0; h < 8; ++h)
        #pragma unroll
        for (int mb = 0; mb < 4; ++mb)
            #pragma unroll
            for (int kb = 0; kb < 4; ++kb) {
                const float* p = part2 + (((long)(h * 32 + b) * 4 + mb) * 4 + kb) * 2;
                l0 += p[0]; l1 += p[1];
            }
    const float s0 = 1.f / (1.f + expf(-l0));
    const float s1 = 1.f / (1.f + expf(-l1));
    const float mm = fmaxf(s0, s1);
    const float lse = mm + logf(expf(s0 - mm) + expf(s1 - mm));
    out[b * 2] = s0 - lse; out[b * 2 + 1] = s1 - lse;
    out[64 + b * 2] = s0;  out[64 + b * 2 + 1] = s1;
}

extern "C" void kernel_launch(void* const* d_in, const int* in_sizes, int n_in,
                              void* d_out, int out_size, void* d_ws, size_t ws_size,
                              hipStream_t stream) {
    (void)in_sizes; (void)n_in;
    const int*   tokens = (const int*)  d_in[0];
    const float* emb    = (const float*)d_in[1];
    const float* Wq     = (const float*)d_in[2];
    const float* bq     = (const float*)d_in[3];
    const float* Wk     = (const float*)d_in[4];
    const float* bk     = (const float*)d_in[5];
    const float* Wv     = (const float*)d_in[6];
    const float* bv     = (const float*)d_in[7];
    const float* fcw    = (const float*)d_in[8];
    const float* fcb    = (const float*)d_in[9];
    float* out = (float*)d_out;

    char* wsp = (char*)d_ws;
    size_t need = 0;
    auto alloc = [&](size_t bytes) {
        char* p = wsp + need;
        need += (bytes + 255) & ~(size_t)255;
        return p;
    };
    u16*   xb     = (u16*)  alloc(16384L * 1024 * 2);   // embedded tokens bf16
    u16*   WqkT   = (u16*)  alloc(8L * 2048 * 1024 * 2);// stacked Wq/Wk transposed bf16
    u16*   WvT    = (u16*)  alloc(8L * 128 * 1024 * 2); // Wv transposed, padded
    float* bqk    = (float*)alloc(8L * 2048 * 4);
    float* bvp    = (float*)alloc(8L * 128 * 4);
    u16*   QK     = (u16*)  alloc(16384L * 2048 * 2);   // per-head [Q|K] bf16
    u16*   Vt     = (u16*)  alloc(1024L * 16384 * 2);   // all-head V^T bf16 [h*128+v][b*s]
    float* scores = (float*)alloc(32L * 512 * 512 * 4); // per-head scores f32 / attn bf16
    float* part2  = (float*)alloc(8L * 32 * 4 * 4 * 2 * 4);
    if (ws_size < need) {
        hipMemsetAsync(d_out, 0, (size_t)out_size * 4, stream);
        return;
    }

    embed_cast<<<16384, 256, 0, stream>>>(tokens, emb, xb);
    pad_bv<<<4, 256, 0, stream>>>(bv, bvp);
    stack_bias<<<64, 256, 0, stream>>>(bq, bk, bqk);
    transpose_qk<<<dim3(32, 32, 16), dim3(32, 8), 0, stream>>>(Wq, Wk, WqkT);
    transpose_v<<<dim3(32, 4, 8), dim3(32, 8), 0, stream>>>(Wv, WvT);

    // all-head V projection: Vt[n][m] = relu(xb @ WvT^T + bvp), transposed store
    gemm8<true, true, true, true><<<dim3(64, 4, 1), 512, 0, stream>>>(
        xb, WvT, Vt, bvp, 1024, 1024, 1024, 16384, 1.f, 0, 0, 0);

    for (int h = 0; h < 8; ++h) {
        // stacked Q|K projection: QK = relu(xb @ WqkT[h]^T + bqk[h])  [16384][2048]
        gemm8<true, true, false, true><<<dim3(64, 8, 1), 512, 0, stream>>>(
            xb, WqkT + (long)h * 2048 * 1024, QK, bqk + h * 2048,
            1024, 1024, 1024, 2048, 1.f, 0, 0, 0);
        // scores[z] = (Q[z] @ K[z]^T) / 32   f32 [512][512], z = batch
        gemm_bt<false, false, false, false><<<dim3(4, 4, 32), 256, 0, stream>>>(
            QK, QK + 1024, scores, nullptr, 1024, 2048, 2048, 512, 0.03125f,
            512L * 2048, 512L * 2048, 512L * 512);
        softmax_inplace<<<4096, 256, 0, stream>>>(scores);
        // PV + fused FC partials
        pv_fc<<<dim3(4, 4, 32), 256, 0, stream>>>(
            (const u16*)scores, Vt, fcw, part2, h);
    }
    final_k<<<1, 64, 0, stream>>>(part2, fcb, out);
}